// Round 7
// baseline (195.243 us; speedup 1.0000x reference)
//
#include <hip/hip_runtime.h>

// MultiHeadAttention: B=2,S=2048,D=1024,H=16,dh=64. fp32 in/out, bf16 MFMA internally.
// R14: gemm_qkv dual-output QK-fused blocks (attn/proj/prep unchanged from R13):
//  - bid 0..255: QK-fused block. Stages A-tile ONCE + both B-tiles (Q-col j, K-col j);
//    64 MFMA per wave per K-step between the same two barriers (2x work per stall
//    window vs 32). acc_q+acc_k = 128 VGPR; bq dead before bk loads -> peak ~200.
//    LDS 48KB (As|Bq|Bk). Epilogue = existing C^T epilogue run twice (q w/ scale, k).
//  - bid 256..511: V block, byte-identical to the proven R7 V path.
//  - grid 512 = 2 blocks/CU (one QK + one V per CU in the common case);
//    unit = bid&7 ~ XCD so each XCD's B-panels (512KB) stay L2-resident.
//  - barrier structure (stage -> sync -> compute -> sync) untouched: proven best
//    (R11 dbuf neutral, R12 8-phase regressed).

typedef __attribute__((ext_vector_type(8))) short short8;
typedef __attribute__((ext_vector_type(4))) float f32x4;

#define MFMA_B16(a, b, c) __builtin_amdgcn_mfma_f32_16x16x32_bf16(a, b, c, 0, 0, 0)

#if __has_builtin(__builtin_amdgcn_exp2f)
#define EXP2(x) __builtin_amdgcn_exp2f(x)
#else
#define EXP2(x) exp2f(x)
#endif

static __device__ __forceinline__ unsigned short f2bf(float f) {
    union { float f; unsigned int u; } v;
    v.f = f;
    unsigned int r = (v.u + 0x7fffu + ((v.u >> 16) & 1u)) >> 16;
    return (unsigned short)r;
}

static __device__ __forceinline__ unsigned int pk_bf16(float a, float b) {
#if __has_builtin(__builtin_amdgcn_cvt_pk_bf16_f32)
    typedef __bf16 bf2 __attribute__((ext_vector_type(2)));
    union { bf2 v; unsigned int u; } c;
    c.v = __builtin_amdgcn_cvt_pk_bf16_f32(a, b);
    return c.u;
#else
    return (unsigned int)f2bf(a) | ((unsigned int)f2bf(b) << 16);
#endif
}

static __device__ __forceinline__ void gl_lds16(const void* g, void* l) {
    __builtin_amdgcn_global_load_lds(
        (const __attribute__((address_space(1))) unsigned int*)g,
        (__attribute__((address_space(3))) unsigned int*)l, 16, 0, 0);
}

// ---------------- fused prep: convert x + transpose both weights ----------------
__global__ __launch_bounds__(256) void prep_kernel(const float4* __restrict__ x,
                                                   uint4* __restrict__ xb,
                                                   const float* __restrict__ wqkv,
                                                   unsigned short* __restrict__ wqkvT,
                                                   const float* __restrict__ wproj,
                                                   unsigned short* __restrict__ wprojT) {
    const int bid = blockIdx.x;
    if (bid < 2048) {
        int i = bid * 256 + threadIdx.x;   // 0..524287, 8 floats each
        float4 v0 = x[i * 2], v1 = x[i * 2 + 1];
        uint4 o;
        o.x = pk_bf16(v0.x, v0.y);
        o.y = pk_bf16(v0.z, v0.w);
        o.z = pk_bf16(v1.x, v1.y);
        o.w = pk_bf16(v1.z, v1.w);
        xb[i] = o;
        return;
    }
    __shared__ float t[32][33];
    const float* in;
    unsigned short* out;
    int R, C, bx, by;
    if (bid < 2048 + 3072) {
        int g = bid - 2048;
        in = wqkv; out = wqkvT; R = 1024; C = 3072;
        bx = g % 96; by = g / 96;
    } else {
        int g = bid - 5120;
        in = wproj; out = wprojT; R = 1024; C = 1024;
        bx = g & 31; by = g >> 5;
    }
    const int c0 = bx * 32, r0 = by * 32;
    const int xx = threadIdx.x & 31, yy0 = threadIdx.x >> 5;
    #pragma unroll
    for (int yy = yy0; yy < 32; yy += 8)
        t[yy][xx] = in[(size_t)(r0 + yy) * C + (c0 + xx)];
    __syncthreads();
    #pragma unroll
    for (int yy = yy0; yy < 32; yy += 8)
        out[(size_t)(c0 + yy) * R + (r0 + xx)] = f2bf(t[xx][yy]);
}

// ---------------- QKV GEMM: C[4096x3072] = A * Bt^T (R14 dual-output) ----------------
// bid 0..255: QK-fused (unit=bid&7 = col-pair, row=bid>>3). bid 256..511: V plain.
__global__ __launch_bounds__(256) void gemm_qkv_kernel(const unsigned short* __restrict__ A,
                                                       const unsigned short* __restrict__ Bt,
                                                       const float* __restrict__ bias,
                                                       unsigned short* __restrict__ q,
                                                       unsigned short* __restrict__ k,
                                                       unsigned short* __restrict__ vT) {
    __shared__ unsigned short smem[24576];   // QK: As|Bq|Bk (3x8192). V: As|Bs.
    const int tid = threadIdx.x;
    const int lane = tid & 63, wave = tid >> 6;
    const int l15 = lane & 15, quad = lane >> 4;
    const int wm = wave >> 1, wn = wave & 1;
    const int bid = blockIdx.x;
    const bool isQK = (bid < 256);
    const int unit = bid & 7;                 // col-pair (QK) or v-col (V); ~XCD
    const int row0 = ((bid & 255) >> 3) * 128;
    const int K = 1024;

    int srow[4], scol[4], sdst[4];
    #pragma unroll
    for (int h = 0; h < 4; ++h) {
        int D = h * 256 + wave * 64 + lane;
        srow[h] = D >> 3;
        scol[h] = ((D & 7) ^ (srow[h] & 7)) * 8;
        sdst[h] = (h * 256 + wave * 64) * 8;
    }

    unsigned short* const As = smem;
    unsigned short* const B0 = smem + 8192;
    unsigned short* const B1 = smem + 16384;

    const int b = row0 >> 11;
    const int s0 = row0 & 2047;
    const int hh = unit * 2 + wn;

    if (isQK) {
        const int colq = unit * 128;          // Q cols in Bt
        const int colk = 1024 + unit * 128;   // K cols in Bt
        f32x4 accq[4][4] = {};
        f32x4 acck[4][4] = {};

        for (int kt = 0; kt < K; kt += 64) {
            #pragma unroll
            for (int h = 0; h < 4; ++h) {
                gl_lds16(&A[(size_t)(row0 + srow[h]) * K + kt + scol[h]], &As[sdst[h]]);
                gl_lds16(&Bt[(size_t)(colq + srow[h]) * K + kt + scol[h]], &B0[sdst[h]]);
                gl_lds16(&Bt[(size_t)(colk + srow[h]) * K + kt + scol[h]], &B1[sdst[h]]);
            }
            __syncthreads();
            #pragma unroll
            for (int kk = 0; kk < 2; ++kk) {
                short8 af[4], bf[4];
                #pragma unroll
                for (int i = 0; i < 4; ++i) {
                    int r = wm * 64 + i * 16 + l15;
                    af[i] = *(const short8*)&As[r * 64 + (((kk * 4 + quad) ^ (r & 7)) * 8)];
                }
                // Q cols: load bq, consume, then reuse regs for bk
                #pragma unroll
                for (int j = 0; j < 4; ++j) {
                    int r = wn * 64 + j * 16 + l15;
                    bf[j] = *(const short8*)&B0[r * 64 + (((kk * 4 + quad) ^ (r & 7)) * 8)];
                }
                #pragma unroll
                for (int i = 0; i < 4; ++i)
                    #pragma unroll
                    for (int j = 0; j < 4; ++j)
                        accq[i][j] = MFMA_B16(bf[j], af[i], accq[i][j]);  // C^T
                #pragma unroll
                for (int j = 0; j < 4; ++j) {
                    int r = wn * 64 + j * 16 + l15;
                    bf[j] = *(const short8*)&B1[r * 64 + (((kk * 4 + quad) ^ (r & 7)) * 8)];
                }
                #pragma unroll
                for (int i = 0; i < 4; ++i)
                    #pragma unroll
                    for (int j = 0; j < 4; ++j)
                        acck[i][j] = MFMA_B16(bf[j], af[i], acck[i][j]);  // C^T
            }
            __syncthreads();
        }

        // epilogue: C^T layout, run twice (Q with scale, then K)
        #pragma unroll
        for (int which = 0; which < 2; ++which) {
            unsigned short* dst = which ? k : q;
            const float scale = which ? 1.0f : 0.1803368867f;  // 1/8 * log2(e) for Q
            const float* bb = bias + (which ? colk : colq) + wn * 64;
            f32x4(*acc)[4] = which ? acck : accq;
            #pragma unroll
            for (int i = 0; i < 4; ++i) {
                const int s = s0 + wm * 64 + i * 16 + l15;
                unsigned short* drow = dst + ((size_t)((b * 16 + hh) * 2048 + s)) * 64;
                #pragma unroll
                for (int j = 0; j < 4; ++j) {
                    float4 b4 = ((const float4*)bb)[j * 4 + quad];
                    uint2 pv;
                    pv.x = pk_bf16((acc[i][j][0] + b4.x) * scale, (acc[i][j][1] + b4.y) * scale);
                    pv.y = pk_bf16((acc[i][j][2] + b4.z) * scale, (acc[i][j][3] + b4.w) * scale);
                    *(uint2*)&drow[j * 16 + quad * 4] = pv;
                }
            }
        }
    } else {
        const int colv = 2048 + unit * 128;   // V cols in Bt
        f32x4 acc[4][4] = {};

        for (int kt = 0; kt < K; kt += 64) {
            #pragma unroll
            for (int h = 0; h < 4; ++h) {
                gl_lds16(&A[(size_t)(row0 + srow[h]) * K + kt + scol[h]], &As[sdst[h]]);
                gl_lds16(&Bt[(size_t)(colv + srow[h]) * K + kt + scol[h]], &B0[sdst[h]]);
            }
            __syncthreads();
            #pragma unroll
            for (int kk = 0; kk < 2; ++kk) {
                short8 af[4], bf[4];
                #pragma unroll
                for (int i = 0; i < 4; ++i) {
                    int r = wm * 64 + i * 16 + l15;
                    af[i] = *(const short8*)&As[r * 64 + (((kk * 4 + quad) ^ (r & 7)) * 8)];
                }
                #pragma unroll
                for (int j = 0; j < 4; ++j) {
                    int r = wn * 64 + j * 16 + l15;
                    bf[j] = *(const short8*)&B0[r * 64 + (((kk * 4 + quad) ^ (r & 7)) * 8)];
                }
                #pragma unroll
                for (int i = 0; i < 4; ++i)
                    #pragma unroll
                    for (int j = 0; j < 4; ++j)
                        acc[i][j] = MFMA_B16(af[i], bf[j], acc[i][j]);  // C (unswapped)
            }
            __syncthreads();
        }

        // C: lane holds s = wm*64 + i*16 + quad*4 + {0..3} for d = j*16 + l15
        const float* bb = bias + colv + wn * 64;
        #pragma unroll
        for (int j = 0; j < 4; ++j) {
            const int d = j * 16 + l15;
            const float bv = bb[d];
            unsigned short* drow = vT + ((size_t)((b * 16 + hh) * 64 + d)) * 2048 + s0;
            #pragma unroll
            for (int i = 0; i < 4; ++i) {
                uint2 pv;
                pv.x = pk_bf16(acc[i][j][0] + bv, acc[i][j][1] + bv);
                pv.y = pk_bf16(acc[i][j][2] + bv, acc[i][j][3] + bv);
                *(uint2*)&drow[wm * 64 + i * 16 + quad * 4] = pv;
            }
        }
    }
}

// ---------------- proj GEMM: out[4096x1024] fp32 = A * Bt^T + bias (R7 form) -------
__global__ __launch_bounds__(256) void gemm_proj_kernel(const unsigned short* __restrict__ A,
                                                        const unsigned short* __restrict__ Bt,
                                                        const float* __restrict__ bias,
                                                        float* __restrict__ out) {
    __shared__ unsigned short As[128 * 64];
    __shared__ unsigned short Bs[64 * 64];
    const int tid = threadIdx.x;
    const int lane = tid & 63, wave = tid >> 6;
    const int l15 = lane & 15, quad = lane >> 4;
    const int wm = wave >> 1, wn = wave & 1;
    const int row0 = blockIdx.y * 128, col0 = blockIdx.x * 64;
    const int K = 1024;

    int srow[4], scol[4], sdst[4];
    #pragma unroll
    for (int h = 0; h < 4; ++h) {
        int D = h * 256 + wave * 64 + lane;
        srow[h] = D >> 3;
        scol[h] = ((D & 7) ^ (srow[h] & 7)) * 8;
        sdst[h] = (h * 256 + wave * 64) * 8;
    }

    f32x4 acc[4][2] = {};

    for (int kt = 0; kt < K; kt += 64) {
        #pragma unroll
        for (int h = 0; h < 4; ++h)
            gl_lds16(&A[(size_t)(row0 + srow[h]) * K + kt + scol[h]], &As[sdst[h]]);
        #pragma unroll
        for (int h = 0; h < 2; ++h)
            gl_lds16(&Bt[(size_t)(col0 + srow[h]) * K + kt + scol[h]], &Bs[sdst[h]]);
        __syncthreads();
        #pragma unroll
        for (int kk = 0; kk < 2; ++kk) {
            short8 af[4], bf[2];
            #pragma unroll
            for (int i = 0; i < 4; ++i) {
                int r = wm * 64 + i * 16 + l15;
                af[i] = *(const short8*)&As[r * 64 + (((kk * 4 + quad) ^ (r & 7)) * 8)];
            }
            #pragma unroll
            for (int j = 0; j < 2; ++j) {
                int r = wn * 32 + j * 16 + l15;
                bf[j] = *(const short8*)&Bs[r * 64 + (((kk * 4 + quad) ^ (r & 7)) * 8)];
            }
            #pragma unroll
            for (int i = 0; i < 4; ++i)
                #pragma unroll
                for (int j = 0; j < 2; ++j)
                    acc[i][j] = MFMA_B16(bf[j], af[i], acc[i][j]);  // C^T
        }
        __syncthreads();
    }

    const float* bb = bias + col0 + wn * 32;
    #pragma unroll
    for (int i = 0; i < 4; ++i) {
        const int row = row0 + wm * 64 + i * 16 + l15;
        #pragma unroll
        for (int j = 0; j < 2; ++j) {
            float4 b4 = ((const float4*)bb)[j * 4 + quad];
            float4 ov;
            ov.x = acc[i][j][0] + b4.x;
            ov.y = acc[i][j][1] + b4.y;
            ov.z = acc[i][j][2] + b4.z;
            ov.w = acc[i][j][3] + b4.w;
            *(float4*)&out[(size_t)row * 1024 + col0 + wn * 32 + j * 16 + quad * 4] = ov;
        }
    }
}

// ---------------- flash attention (R13: KVBLK=128, all-wave-active blocks) -------------
// smem (shorts): [0..16383] Ks[2][2 halves][64x64] | [16384..32767] Vs[2][2][64x64]
//                | [32768..40959] Pw[8][1024].  Total 80KB -> 2 blocks/CU.
__global__ __launch_bounds__(512) void attn_kernel(const unsigned short* __restrict__ Q,
                                                   const unsigned short* __restrict__ Kg,
                                                   const unsigned short* __restrict__ Vt,
                                                   const int* __restrict__ idx,
                                                   const float* __restrict__ weight,
                                                   const int* __restrict__ forcing,
                                                   unsigned short* __restrict__ O) {
    __shared__ unsigned short smem[40960];

    const int tid = threadIdx.x;
    const int lane = tid & 63, wave = tid >> 6;
    const int l15 = lane & 15, quad = lane >> 4;
    const int bid = blockIdx.x;
    const int qh = bid >> 8;
    const int rem = bid & 255;
    const int xcd = rem & 7;
    const int head = (rem >> 3) & 3;
    const int g2 = rem >> 5;          // 0..7
    const int p = qh ? (7 - g2) : (8 + g2);
    const int bh = xcd * 4 + head;
    const int b = bh >> 4, hh = bh & 15;
    const unsigned short* Qb = Q + (size_t)bh * 2048 * 64;
    const unsigned short* Kh = Kg + (size_t)bh * 2048 * 64;
    const unsigned short* Vh = Vt + (size_t)bh * 2048 * 64;

    const int idxb = idx[b];
    const float lw = (forcing[0] != 0) ? __log2f(weight[0]) : 0.0f;

    const int wq = 2 * p + ((wave < 4) ? 1 : 0);
    const int wg = wave & 3;
    const int q0 = wq * 64 + wg * 16;
    const int qrow = q0 + l15;
    const int nkb = p + 1;            // 128-wide k-tiles

    const int rS = tid >> 3;
    const int cS8 = ((tid & 7) ^ (rS & 7)) * 8;

    short8 aq0 = *(const short8*)&Qb[(q0 + l15) * 64 + quad * 8];
    short8 aq1 = *(const short8*)&Qb[(q0 + l15) * 64 + 32 + quad * 8];

    const short8 ones8 = {0x3F80, 0x3F80, 0x3F80, 0x3F80, 0x3F80, 0x3F80, 0x3F80, 0x3F80};

    f32x4 o[4] = {};
    f32x4 lsum = {};

    gl_lds16(Kh + (size_t)rS * 64 + cS8,             &smem[tid * 8]);
    gl_lds16(Kh + (size_t)(64 + rS) * 64 + cS8,      &smem[4096 + tid * 8]);
    gl_lds16(Vh + (size_t)rS * 2048 + cS8,           &smem[16384 + tid * 8]);
    gl_lds16(Vh + (size_t)rS * 2048 + 64 + cS8,      &smem[16384 + 4096 + tid * 8]);
    __syncthreads();

    unsigned short* const pwb = &smem[32768 + wave * 1024];
    const int pwr = l15 * 64;
    const int pa7 = l15 & 7;

    for (int kb = 0; kb < nkb; ++kb) {
        const int cur = kb & 1;
        const int kbase = kb * 128;
        if (kb + 1 < nkb) {
            const int nb = kbase + 128;
            gl_lds16(Kh + (size_t)(nb + rS) * 64 + cS8,      &smem[(cur ^ 1) * 8192 + tid * 8]);
            gl_lds16(Kh + (size_t)(nb + 64 + rS) * 64 + cS8, &smem[(cur ^ 1) * 8192 + 4096 + tid * 8]);
            gl_lds16(Vh + (size_t)rS * 2048 + nb + cS8,      &smem[16384 + (cur ^ 1) * 8192 + tid * 8]);
            gl_lds16(Vh + (size_t)rS * 2048 + nb + 64 + cS8, &smem[16384 + (cur ^ 1) * 8192 + 4096 + tid * 8]);
        }

        const unsigned short* KsP = &smem[cur * 8192];
        const unsigned short* VsP = &smem[16384 + cur * 8192];

        const bool fullF = (kbase >= idxb);
        const bool bndF = (!fullF) && (kbase + 127 >= idxb);
        const float zu = fullF ? lw : 0.0f;

        f32x4 sT[8];
        #pragma unroll
        for (int kt = 0; kt < 8; ++kt) {
            const int lr = (kt & 3) * 16 + l15;
            const unsigned short* Kp = KsP + (kt >> 2) * 4096;
            short8 k0 = *(const short8*)&Kp[lr * 64 + ((quad ^ (lr & 7)) * 8)];
            short8 k1 = *(const short8*)&Kp[lr * 64 + (((4 + quad) ^ (lr & 7)) * 8)];
            f32x4 z;
            if (!bndF) {
                z[0] = zu; z[1] = zu; z[2] = zu; z[3] = zu;
            } else {
                #pragma unroll
                for (int r = 0; r < 4; ++r)
                    z[r] = (kbase + kt * 16 + quad * 4 + r >= idxb) ? lw : 0.0f;
            }
            z = MFMA_B16(k0, aq0, z);
            z = MFMA_B16(k1, aq1, z);
            sT[kt] = z;
        }

        if (kb == nkb - 1) {
            #pragma unroll
            for (int kt = 0; kt < 8; ++kt)
                #pragma unroll
                for (int r = 0; r < 4; ++r)
                    if (kbase + kt * 16 + quad * 4 + r > qrow) sT[kt][r] = -3.0e38f;
        }

        #pragma unroll
        for (int kt = 0; kt < 8; ++kt)
            #pragma unroll
            for (int r = 0; r < 4; ++r)
                sT[kt][r] = EXP2(sT[kt][r]);

        #pragma unroll
        for (int h = 0; h < 2; ++h) {
            #pragma unroll
            for (int kt = 0; kt < 4; ++kt) {
                f32x4 s = sT[h * 4 + kt];
                unsigned int* pw = (unsigned int*)&pwb[pwr +
                    (((kt * 2 + (quad >> 1)) ^ pa7) * 8) + (quad & 1) * 4];
                pw[0] = pk_bf16(s[0], s[1]);
                pw[1] = pk_bf16(s[2], s[3]);
            }

            short8 bp0 = *(const short8*)&pwb[pwr + ((quad ^ pa7) * 8)];
            short8 bp1 = *(const short8*)&pwb[pwr + (((4 + quad) ^ pa7) * 8)];

            lsum = MFMA_B16(ones8, bp0, lsum);
            lsum = MFMA_B16(ones8, bp1, lsum);

            const unsigned short* Vp = VsP + h * 4096;
            #pragma unroll
            for (int dt = 0; dt < 4; ++dt) {
                const int row = dt * 16 + l15;
                short8 vf0 = *(const short8*)&Vp[row * 64 + ((quad ^ (row & 7)) * 8)];
                short8 vf1 = *(const short8*)&Vp[row * 64 + (((4 + quad) ^ (row & 7)) * 8)];
                f32x4 oo = o[dt];
                oo = MFMA_B16(vf0, bp0, oo);
                oo = MFMA_B16(vf1, bp1, oo);
                o[dt] = oo;
            }
        }

        __syncthreads();
    }

    const float inv = 1.0f / lsum[0];
    unsigned short* sc = &smem[wave * 1152];
    #pragma unroll
    for (int dt = 0; dt < 4; ++dt)
        #pragma unroll
        for (int r = 0; r < 4; ++r)
            sc[l15 * 72 + dt * 16 + quad * 4 + r] = f2bf(o[dt][r] * inv);
    const size_t rowoff = ((size_t)(b * 2048 + q0 + l15)) * 1024 + hh * 64;
    #pragma unroll
    for (int h = 0; h < 2; ++h) {
        short8 v8 = *(const short8*)&sc[l15 * 72 + quad * 16 + h * 8];
        *(short8*)&O[rowoff + quad * 16 + h * 8] = v8;
    }
}

extern "C" void kernel_launch(void* const* d_in, const int* in_sizes, int n_in,
                              void* d_out, int out_size, void* d_ws, size_t ws_size,
                              hipStream_t stream) {
    const float* x        = (const float*)d_in[0];
    const int*   idx      = (const int*)d_in[1];
    const float* weight   = (const float*)d_in[2];
    const int*   forcing  = (const int*)d_in[3];
    const float* w_qkv    = (const float*)d_in[4];
    const float* b_qkv    = (const float*)d_in[5];
    const float* w_proj   = (const float*)d_in[6];
    const float* b_proj   = (const float*)d_in[7];
    float* out = (float*)d_out;

    char* ws = (char*)d_ws;
    unsigned short* xb      = (unsigned short*)(ws);              // 8 MB (reused: attn_out)
    unsigned short* wqkvT   = (unsigned short*)(ws + 8388608);    // 6 MB
    unsigned short* wprojT  = (unsigned short*)(ws + 14680064);   // 2 MB
    unsigned short* qbuf    = (unsigned short*)(ws + 16777216);   // 8 MB
    unsigned short* kbuf    = (unsigned short*)(ws + 25165824);   // 8 MB
    unsigned short* vTbuf   = (unsigned short*)(ws + 33554432);   // 8 MB
    unsigned short* attn_out = xb;  // xb dead after gemm_qkv

    prep_kernel<<<6144, 256, 0, stream>>>((const float4*)x, (uint4*)xb,
                                          w_qkv, wqkvT, w_proj, wprojT);
    gemm_qkv_kernel<<<512, 256, 0, stream>>>(xb, wqkvT, b_qkv, qbuf, kbuf, vTbuf);
    attn_kernel<<<512, 512, 0, stream>>>(qbuf, kbuf, vTbuf, idx, weight, forcing, attn_out);
    gemm_proj_kernel<<<dim3(16, 32), 256, 0, stream>>>(attn_out, wprojT, b_proj, out);
}

// Round 8
// 181.488 us; speedup vs baseline: 1.0758x; 1.0758x over previous
//
#include <hip/hip_runtime.h>

// MultiHeadAttention: B=2,S=2048,D=1024,H=16,dh=64. fp32 in/out, bf16 MFMA internally.
// R15: byte-exact revert to R13 (best measured 180.4us) + ONE isolated change:
//  - attn: s_setprio(1)/(0) around QK and PV MFMA clusters (T5). attn has 2
//    independent blocks/CU at staggered phases -> setprio applies (m191 +4-7%);
//    GEMMs stay setprio-free (m190: hurts lockstep).
//  - gemm_qkv/gemm_proj/prep: R13/R7 proven forms. qkv structure experiments closed
//    (dbuf R11 neutral, 8-phase R12 regressed, QK-fuse R14 regressed).

typedef __attribute__((ext_vector_type(8))) short short8;
typedef __attribute__((ext_vector_type(4))) float f32x4;

#define MFMA_B16(a, b, c) __builtin_amdgcn_mfma_f32_16x16x32_bf16(a, b, c, 0, 0, 0)

#if __has_builtin(__builtin_amdgcn_exp2f)
#define EXP2(x) __builtin_amdgcn_exp2f(x)
#else
#define EXP2(x) exp2f(x)
#endif

static __device__ __forceinline__ unsigned short f2bf(float f) {
    union { float f; unsigned int u; } v;
    v.f = f;
    unsigned int r = (v.u + 0x7fffu + ((v.u >> 16) & 1u)) >> 16;
    return (unsigned short)r;
}

static __device__ __forceinline__ unsigned int pk_bf16(float a, float b) {
#if __has_builtin(__builtin_amdgcn_cvt_pk_bf16_f32)
    typedef __bf16 bf2 __attribute__((ext_vector_type(2)));
    union { bf2 v; unsigned int u; } c;
    c.v = __builtin_amdgcn_cvt_pk_bf16_f32(a, b);
    return c.u;
#else
    return (unsigned int)f2bf(a) | ((unsigned int)f2bf(b) << 16);
#endif
}

static __device__ __forceinline__ void gl_lds16(const void* g, void* l) {
    __builtin_amdgcn_global_load_lds(
        (const __attribute__((address_space(1))) unsigned int*)g,
        (__attribute__((address_space(3))) unsigned int*)l, 16, 0, 0);
}

// ---------------- fused prep: convert x + transpose both weights ----------------
__global__ __launch_bounds__(256) void prep_kernel(const float4* __restrict__ x,
                                                   uint4* __restrict__ xb,
                                                   const float* __restrict__ wqkv,
                                                   unsigned short* __restrict__ wqkvT,
                                                   const float* __restrict__ wproj,
                                                   unsigned short* __restrict__ wprojT) {
    const int bid = blockIdx.x;
    if (bid < 2048) {
        int i = bid * 256 + threadIdx.x;   // 0..524287, 8 floats each
        float4 v0 = x[i * 2], v1 = x[i * 2 + 1];
        uint4 o;
        o.x = pk_bf16(v0.x, v0.y);
        o.y = pk_bf16(v0.z, v0.w);
        o.z = pk_bf16(v1.x, v1.y);
        o.w = pk_bf16(v1.z, v1.w);
        xb[i] = o;
        return;
    }
    __shared__ float t[32][33];
    const float* in;
    unsigned short* out;
    int R, C, bx, by;
    if (bid < 2048 + 3072) {
        int g = bid - 2048;
        in = wqkv; out = wqkvT; R = 1024; C = 3072;
        bx = g % 96; by = g / 96;
    } else {
        int g = bid - 5120;
        in = wproj; out = wprojT; R = 1024; C = 1024;
        bx = g & 31; by = g >> 5;
    }
    const int c0 = bx * 32, r0 = by * 32;
    const int xx = threadIdx.x & 31, yy0 = threadIdx.x >> 5;
    #pragma unroll
    for (int yy = yy0; yy < 32; yy += 8)
        t[yy][xx] = in[(size_t)(r0 + yy) * C + (c0 + xx)];
    __syncthreads();
    #pragma unroll
    for (int yy = yy0; yy < 32; yy += 8)
        out[(size_t)(c0 + yy) * R + (r0 + xx)] = f2bf(t[xx][yy]);
}

// ---------------- QKV GEMM: C[4096x3072] = A * Bt^T (R7 form) ----------------
// blockIdx.x 0..7 = Q (swapped MFMA, scaled), 8..15 = K (swapped), 16..23 = V (unswapped,
// direct b64 stores to vT [bh][d][s]).
__global__ __launch_bounds__(256) void gemm_qkv_kernel(const unsigned short* __restrict__ A,
                                                       const unsigned short* __restrict__ Bt,
                                                       const float* __restrict__ bias,
                                                       unsigned short* __restrict__ q,
                                                       unsigned short* __restrict__ k,
                                                       unsigned short* __restrict__ vT) {
    __shared__ unsigned short As[128 * 64];
    __shared__ unsigned short Bs[128 * 64];
    const int tid = threadIdx.x;
    const int lane = tid & 63, wave = tid >> 6;
    const int l15 = lane & 15, quad = lane >> 4;
    const int wm = wave >> 1, wn = wave & 1;
    const int row0 = blockIdx.y * 128, col0 = blockIdx.x * 128;
    const int K = 1024;
    const bool isV = (blockIdx.x >= 16);

    int srow[4], scol[4], sdst[4];
    #pragma unroll
    for (int h = 0; h < 4; ++h) {
        int D = h * 256 + wave * 64 + lane;
        srow[h] = D >> 3;
        scol[h] = ((D & 7) ^ (srow[h] & 7)) * 8;
        sdst[h] = (h * 256 + wave * 64) * 8;
    }

    f32x4 acc[4][4] = {};

    for (int kt = 0; kt < K; kt += 64) {
        #pragma unroll
        for (int h = 0; h < 4; ++h) {
            gl_lds16(&A[(size_t)(row0 + srow[h]) * K + kt + scol[h]], &As[sdst[h]]);
            gl_lds16(&Bt[(size_t)(col0 + srow[h]) * K + kt + scol[h]], &Bs[sdst[h]]);
        }
        __syncthreads();
        #pragma unroll
        for (int kk = 0; kk < 2; ++kk) {
            short8 af[4], bf[4];
            #pragma unroll
            for (int i = 0; i < 4; ++i) {
                int r = wm * 64 + i * 16 + l15;
                af[i] = *(const short8*)&As[r * 64 + (((kk * 4 + quad) ^ (r & 7)) * 8)];
            }
            #pragma unroll
            for (int j = 0; j < 4; ++j) {
                int r = wn * 64 + j * 16 + l15;
                bf[j] = *(const short8*)&Bs[r * 64 + (((kk * 4 + quad) ^ (r & 7)) * 8)];
            }
            if (isV) {
                #pragma unroll
                for (int i = 0; i < 4; ++i)
                    #pragma unroll
                    for (int j = 0; j < 4; ++j)
                        acc[i][j] = MFMA_B16(af[i], bf[j], acc[i][j]);  // C
            } else {
                #pragma unroll
                for (int i = 0; i < 4; ++i)
                    #pragma unroll
                    for (int j = 0; j < 4; ++j)
                        acc[i][j] = MFMA_B16(bf[j], af[i], acc[i][j]);  // C^T
            }
        }
        __syncthreads();
    }

    const int b = row0 >> 11;
    const int s0 = row0 & 2047;
    const float* bb = bias + col0 + wn * 64;

    if (!isV) {
        // C^T: lane holds d = j*16 + quad*4 + {0..3} for s = wm*64 + i*16 + l15
        const int which = blockIdx.x >> 3;  // 0=Q, 1=K
        unsigned short* dst = which ? k : q;
        const float scale = which ? 1.0f : 0.1803368867f;  // 1/8 * log2(e) for Q
        const int hh = ((blockIdx.x & 7) << 1) + wn;
        #pragma unroll
        for (int i = 0; i < 4; ++i) {
            const int s = s0 + wm * 64 + i * 16 + l15;
            unsigned short* drow = dst + ((size_t)((b * 16 + hh) * 2048 + s)) * 64;
            #pragma unroll
            for (int j = 0; j < 4; ++j) {
                float4 b4 = ((const float4*)bb)[j * 4 + quad];
                uint2 pv;
                pv.x = pk_bf16((acc[i][j][0] + b4.x) * scale, (acc[i][j][1] + b4.y) * scale);
                pv.y = pk_bf16((acc[i][j][2] + b4.z) * scale, (acc[i][j][3] + b4.w) * scale);
                *(uint2*)&drow[j * 16 + quad * 4] = pv;
            }
        }
    } else {
        // C: lane holds s = wm*64 + i*16 + quad*4 + {0..3} for d = j*16 + l15
        const int hh = ((blockIdx.x - 16) << 1) + wn;
        #pragma unroll
        for (int j = 0; j < 4; ++j) {
            const int d = j * 16 + l15;
            const float bv = bb[d];
            unsigned short* drow = vT + ((size_t)((b * 16 + hh) * 64 + d)) * 2048 + s0;
            #pragma unroll
            for (int i = 0; i < 4; ++i) {
                uint2 pv;
                pv.x = pk_bf16(acc[i][j][0] + bv, acc[i][j][1] + bv);
                pv.y = pk_bf16(acc[i][j][2] + bv, acc[i][j][3] + bv);
                *(uint2*)&drow[wm * 64 + i * 16 + quad * 4] = pv;
            }
        }
    }
}

// ---------------- proj GEMM: out[4096x1024] fp32 = A * Bt^T + bias (R7 form) -------
__global__ __launch_bounds__(256) void gemm_proj_kernel(const unsigned short* __restrict__ A,
                                                        const unsigned short* __restrict__ Bt,
                                                        const float* __restrict__ bias,
                                                        float* __restrict__ out) {
    __shared__ unsigned short As[128 * 64];
    __shared__ unsigned short Bs[64 * 64];
    const int tid = threadIdx.x;
    const int lane = tid & 63, wave = tid >> 6;
    const int l15 = lane & 15, quad = lane >> 4;
    const int wm = wave >> 1, wn = wave & 1;
    const int row0 = blockIdx.y * 128, col0 = blockIdx.x * 64;
    const int K = 1024;

    int srow[4], scol[4], sdst[4];
    #pragma unroll
    for (int h = 0; h < 4; ++h) {
        int D = h * 256 + wave * 64 + lane;
        srow[h] = D >> 3;
        scol[h] = ((D & 7) ^ (srow[h] & 7)) * 8;
        sdst[h] = (h * 256 + wave * 64) * 8;
    }

    f32x4 acc[4][2] = {};

    for (int kt = 0; kt < K; kt += 64) {
        #pragma unroll
        for (int h = 0; h < 4; ++h)
            gl_lds16(&A[(size_t)(row0 + srow[h]) * K + kt + scol[h]], &As[sdst[h]]);
        #pragma unroll
        for (int h = 0; h < 2; ++h)
            gl_lds16(&Bt[(size_t)(col0 + srow[h]) * K + kt + scol[h]], &Bs[sdst[h]]);
        __syncthreads();
        #pragma unroll
        for (int kk = 0; kk < 2; ++kk) {
            short8 af[4], bf[2];
            #pragma unroll
            for (int i = 0; i < 4; ++i) {
                int r = wm * 64 + i * 16 + l15;
                af[i] = *(const short8*)&As[r * 64 + (((kk * 4 + quad) ^ (r & 7)) * 8)];
            }
            #pragma unroll
            for (int j = 0; j < 2; ++j) {
                int r = wn * 32 + j * 16 + l15;
                bf[j] = *(const short8*)&Bs[r * 64 + (((kk * 4 + quad) ^ (r & 7)) * 8)];
            }
            #pragma unroll
            for (int i = 0; i < 4; ++i)
                #pragma unroll
                for (int j = 0; j < 2; ++j)
                    acc[i][j] = MFMA_B16(bf[j], af[i], acc[i][j]);  // C^T
        }
        __syncthreads();
    }

    const float* bb = bias + col0 + wn * 32;
    #pragma unroll
    for (int i = 0; i < 4; ++i) {
        const int row = row0 + wm * 64 + i * 16 + l15;
        #pragma unroll
        for (int j = 0; j < 2; ++j) {
            float4 b4 = ((const float4*)bb)[j * 4 + quad];
            float4 ov;
            ov.x = acc[i][j][0] + b4.x;
            ov.y = acc[i][j][1] + b4.y;
            ov.z = acc[i][j][2] + b4.z;
            ov.w = acc[i][j][3] + b4.w;
            *(float4*)&out[(size_t)row * 1024 + col0 + wn * 32 + j * 16 + quad * 4] = ov;
        }
    }
}

// ---------------- flash attention (R13 + T5 setprio) -------------
// smem (shorts): [0..16383] Ks[2][2 halves][64x64] | [16384..32767] Vs[2][2][64x64]
//                | [32768..40959] Pw[8][1024].  Total 80KB -> 2 blocks/CU.
__global__ __launch_bounds__(512) void attn_kernel(const unsigned short* __restrict__ Q,
                                                   const unsigned short* __restrict__ Kg,
                                                   const unsigned short* __restrict__ Vt,
                                                   const int* __restrict__ idx,
                                                   const float* __restrict__ weight,
                                                   const int* __restrict__ forcing,
                                                   unsigned short* __restrict__ O) {
    __shared__ unsigned short smem[40960];

    const int tid = threadIdx.x;
    const int lane = tid & 63, wave = tid >> 6;
    const int l15 = lane & 15, quad = lane >> 4;
    const int bid = blockIdx.x;
    // bid<256 = long blocks (p=8..15), bid>=256 = complements (p=7..0) with the same
    // rem -> CU-paired blocks run 17 tiles total and share the same head's K/V stream.
    // rem&7 ~ XCD -> 4 heads per XCD (2MB K/V in its L2).
    const int qh = bid >> 8;
    const int rem = bid & 255;
    const int xcd = rem & 7;
    const int head = (rem >> 3) & 3;
    const int g2 = rem >> 5;          // 0..7
    const int p = qh ? (7 - g2) : (8 + g2);
    const int bh = xcd * 4 + head;
    const int b = bh >> 4, hh = bh & 15;
    const unsigned short* Qb = Q + (size_t)bh * 2048 * 64;
    const unsigned short* Kh = Kg + (size_t)bh * 2048 * 64;
    const unsigned short* Vh = Vt + (size_t)bh * 2048 * 64;

    const int idxb = idx[b];
    const float lw = (forcing[0] != 0) ? __log2f(weight[0]) : 0.0f;

    // q-block rows [128p, 128p+128): waves 0-3 -> upper 64, waves 4-7 -> lower 64.
    const int wq = 2 * p + ((wave < 4) ? 1 : 0);
    const int wg = wave & 3;
    const int q0 = wq * 64 + wg * 16;
    const int qrow = q0 + l15;
    const int nkb = p + 1;            // 128-wide k-tiles

    const int rS = tid >> 3;
    const int cS8 = ((tid & 7) ^ (rS & 7)) * 8;

    short8 aq0 = *(const short8*)&Qb[(q0 + l15) * 64 + quad * 8];
    short8 aq1 = *(const short8*)&Qb[(q0 + l15) * 64 + 32 + quad * 8];

    const short8 ones8 = {0x3F80, 0x3F80, 0x3F80, 0x3F80, 0x3F80, 0x3F80, 0x3F80, 0x3F80};

    f32x4 o[4] = {};
    f32x4 lsum = {};

    gl_lds16(Kh + (size_t)rS * 64 + cS8,             &smem[tid * 8]);
    gl_lds16(Kh + (size_t)(64 + rS) * 64 + cS8,      &smem[4096 + tid * 8]);
    gl_lds16(Vh + (size_t)rS * 2048 + cS8,           &smem[16384 + tid * 8]);
    gl_lds16(Vh + (size_t)rS * 2048 + 64 + cS8,      &smem[16384 + 4096 + tid * 8]);
    __syncthreads();

    unsigned short* const pwb = &smem[32768 + wave * 1024];
    const int pwr = l15 * 64;
    const int pa7 = l15 & 7;

    for (int kb = 0; kb < nkb; ++kb) {
        const int cur = kb & 1;
        const int kbase = kb * 128;
        if (kb + 1 < nkb) {
            const int nb = kbase + 128;
            gl_lds16(Kh + (size_t)(nb + rS) * 64 + cS8,      &smem[(cur ^ 1) * 8192 + tid * 8]);
            gl_lds16(Kh + (size_t)(nb + 64 + rS) * 64 + cS8, &smem[(cur ^ 1) * 8192 + 4096 + tid * 8]);
            gl_lds16(Vh + (size_t)rS * 2048 + nb + cS8,      &smem[16384 + (cur ^ 1) * 8192 + tid * 8]);
            gl_lds16(Vh + (size_t)rS * 2048 + nb + 64 + cS8, &smem[16384 + (cur ^ 1) * 8192 + 4096 + tid * 8]);
        }

        const unsigned short* KsP = &smem[cur * 8192];
        const unsigned short* VsP = &smem[16384 + cur * 8192];

        const bool fullF = (kbase >= idxb);
        const bool bndF = (!fullF) && (kbase + 127 >= idxb);
        const float zu = fullF ? lw : 0.0f;

        // QK^T over the full 128-wide tile (two 64-halves of K)
        f32x4 sT[8];
        #pragma unroll
        for (int kt = 0; kt < 8; ++kt) {
            const int lr = (kt & 3) * 16 + l15;
            const unsigned short* Kp = KsP + (kt >> 2) * 4096;
            short8 k0 = *(const short8*)&Kp[lr * 64 + ((quad ^ (lr & 7)) * 8)];
            short8 k1 = *(const short8*)&Kp[lr * 64 + (((4 + quad) ^ (lr & 7)) * 8)];
            f32x4 z;
            if (!bndF) {
                z[0] = zu; z[1] = zu; z[2] = zu; z[3] = zu;
            } else {
                #pragma unroll
                for (int r = 0; r < 4; ++r)
                    z[r] = (kbase + kt * 16 + quad * 4 + r >= idxb) ? lw : 0.0f;
            }
            __builtin_amdgcn_s_setprio(1);
            z = MFMA_B16(k0, aq0, z);
            z = MFMA_B16(k1, aq1, z);
            __builtin_amdgcn_s_setprio(0);
            sT[kt] = z;
        }

        if (kb == nkb - 1) {   // diagonal 128-tile (covers both wave-groups' masking)
            #pragma unroll
            for (int kt = 0; kt < 8; ++kt)
                #pragma unroll
                for (int r = 0; r < 4; ++r)
                    if (kbase + kt * 16 + quad * 4 + r > qrow) sT[kt][r] = -3.0e38f;
        }

        #pragma unroll
        for (int kt = 0; kt < 8; ++kt)
            #pragma unroll
            for (int r = 0; r < 4; ++r)
                sT[kt][r] = EXP2(sT[kt][r]);

        // P pack + lsum + PV, one 64-half at a time (reuses 1KB pwb per wave)
        #pragma unroll
        for (int h = 0; h < 2; ++h) {
            #pragma unroll
            for (int kt = 0; kt < 4; ++kt) {
                f32x4 s = sT[h * 4 + kt];
                unsigned int* pw = (unsigned int*)&pwb[pwr +
                    (((kt * 2 + (quad >> 1)) ^ pa7) * 8) + (quad & 1) * 4];
                pw[0] = pk_bf16(s[0], s[1]);
                pw[1] = pk_bf16(s[2], s[3]);
            }

            short8 bp0 = *(const short8*)&pwb[pwr + ((quad ^ pa7) * 8)];
            short8 bp1 = *(const short8*)&pwb[pwr + (((4 + quad) ^ pa7) * 8)];

            __builtin_amdgcn_s_setprio(1);
            lsum = MFMA_B16(ones8, bp0, lsum);
            lsum = MFMA_B16(ones8, bp1, lsum);
            __builtin_amdgcn_s_setprio(0);

            const unsigned short* Vp = VsP + h * 4096;
            #pragma unroll
            for (int dt = 0; dt < 4; ++dt) {
                const int row = dt * 16 + l15;
                short8 vf0 = *(const short8*)&Vp[row * 64 + ((quad ^ (row & 7)) * 8)];
                short8 vf1 = *(const short8*)&Vp[row * 64 + (((4 + quad) ^ (row & 7)) * 8)];
                f32x4 oo = o[dt];
                __builtin_amdgcn_s_setprio(1);
                oo = MFMA_B16(vf0, bp0, oo);
                oo = MFMA_B16(vf1, bp1, oo);
                __builtin_amdgcn_s_setprio(0);
                o[dt] = oo;
            }
        }

        __syncthreads();
    }

    // epilogue: per-wave transpose through LDS scratch (8 waves x 1152 shorts, disjoint)
    const float inv = 1.0f / lsum[0];
    unsigned short* sc = &smem[wave * 1152];
    #pragma unroll
    for (int dt = 0; dt < 4; ++dt)
        #pragma unroll
        for (int r = 0; r < 4; ++r)
            sc[l15 * 72 + dt * 16 + quad * 4 + r] = f2bf(o[dt][r] * inv);
    const size_t rowoff = ((size_t)(b * 2048 + q0 + l15)) * 1024 + hh * 64;
    #pragma unroll
    for (int h = 0; h < 2; ++h) {
        short8 v8 = *(const short8*)&sc[l15 * 72 + quad * 16 + h * 8];
        *(short8*)&O[rowoff + quad * 16 + h * 8] = v8;
    }
}

extern "C" void kernel_launch(void* const* d_in, const int* in_sizes, int n_in,
                              void* d_out, int out_size, void* d_ws, size_t ws_size,
                              hipStream_t stream) {
    const float* x        = (const float*)d_in[0];
    const int*   idx      = (const int*)d_in[1];
    const float* weight   = (const float*)d_in[2];
    const int*   forcing  = (const int*)d_in[3];
    const float* w_qkv    = (const float*)d_in[4];
    const float* b_qkv    = (const float*)d_in[5];
    const float* w_proj   = (const float*)d_in[6];
    const float* b_proj   = (const float*)d_in[7];
    float* out = (float*)d_out;

    char* ws = (char*)d_ws;
    unsigned short* xb      = (unsigned short*)(ws);              // 8 MB (reused: attn_out)
    unsigned short* wqkvT   = (unsigned short*)(ws + 8388608);    // 6 MB
    unsigned short* wprojT  = (unsigned short*)(ws + 14680064);   // 2 MB
    unsigned short* qbuf    = (unsigned short*)(ws + 16777216);   // 8 MB
    unsigned short* kbuf    = (unsigned short*)(ws + 25165824);   // 8 MB
    unsigned short* vTbuf   = (unsigned short*)(ws + 33554432);   // 8 MB
    unsigned short* attn_out = xb;  // xb dead after gemm_qkv

    prep_kernel<<<6144, 256, 0, stream>>>((const float4*)x, (uint4*)xb,
                                          w_qkv, wqkvT, w_proj, wprojT);
    gemm_qkv_kernel<<<dim3(24, 32), 256, 0, stream>>>(xb, wqkvT, b_qkv, qbuf, kbuf, vTbuf);
    attn_kernel<<<512, 512, 0, stream>>>(qbuf, kbuf, vTbuf, idx, weight, forcing, attn_out);
    gemm_proj_kernel<<<dim3(16, 32), 256, 0, stream>>>(attn_out, wprojT, b_proj, out);
}

// Round 9
// 178.155 us; speedup vs baseline: 1.0959x; 1.0187x over previous
//
#include <hip/hip_runtime.h>

// MultiHeadAttention: B=2,S=2048,D=1024,H=16,dh=64. fp32 in/out, bf16 MFMA internally.
// R16: attn reverted to byte-exact R13 (T5 setprio removed: null within noise, 181.5 vs
// 180.4). ONE isolated change vs R13: gemm_qkv block mapping -> pure T1 XCD grouping.
//  - 1-D grid 768: xcd=bid&7 owns B-cols {3*xcd..3*xcd+2} (768KB L2-resident/XCD);
//    j=bid>>3 iterates col-within-group fastest so the 3 co-resident blocks per XCD
//    share one A-panel window. R7 structure/LDS/schedule/epilogue untouched.
//  - qkv structure experiments closed (dbuf R11 null, 8-phase R12 regressed, QK-fuse
//    R14 regressed, setprio n/a). This is the last catalogued isolated technique.

typedef __attribute__((ext_vector_type(8))) short short8;
typedef __attribute__((ext_vector_type(4))) float f32x4;

#define MFMA_B16(a, b, c) __builtin_amdgcn_mfma_f32_16x16x32_bf16(a, b, c, 0, 0, 0)

#if __has_builtin(__builtin_amdgcn_exp2f)
#define EXP2(x) __builtin_amdgcn_exp2f(x)
#else
#define EXP2(x) exp2f(x)
#endif

static __device__ __forceinline__ unsigned short f2bf(float f) {
    union { float f; unsigned int u; } v;
    v.f = f;
    unsigned int r = (v.u + 0x7fffu + ((v.u >> 16) & 1u)) >> 16;
    return (unsigned short)r;
}

static __device__ __forceinline__ unsigned int pk_bf16(float a, float b) {
#if __has_builtin(__builtin_amdgcn_cvt_pk_bf16_f32)
    typedef __bf16 bf2 __attribute__((ext_vector_type(2)));
    union { bf2 v; unsigned int u; } c;
    c.v = __builtin_amdgcn_cvt_pk_bf16_f32(a, b);
    return c.u;
#else
    return (unsigned int)f2bf(a) | ((unsigned int)f2bf(b) << 16);
#endif
}

static __device__ __forceinline__ void gl_lds16(const void* g, void* l) {
    __builtin_amdgcn_global_load_lds(
        (const __attribute__((address_space(1))) unsigned int*)g,
        (__attribute__((address_space(3))) unsigned int*)l, 16, 0, 0);
}

// ---------------- fused prep: convert x + transpose both weights ----------------
__global__ __launch_bounds__(256) void prep_kernel(const float4* __restrict__ x,
                                                   uint4* __restrict__ xb,
                                                   const float* __restrict__ wqkv,
                                                   unsigned short* __restrict__ wqkvT,
                                                   const float* __restrict__ wproj,
                                                   unsigned short* __restrict__ wprojT) {
    const int bid = blockIdx.x;
    if (bid < 2048) {
        int i = bid * 256 + threadIdx.x;   // 0..524287, 8 floats each
        float4 v0 = x[i * 2], v1 = x[i * 2 + 1];
        uint4 o;
        o.x = pk_bf16(v0.x, v0.y);
        o.y = pk_bf16(v0.z, v0.w);
        o.z = pk_bf16(v1.x, v1.y);
        o.w = pk_bf16(v1.z, v1.w);
        xb[i] = o;
        return;
    }
    __shared__ float t[32][33];
    const float* in;
    unsigned short* out;
    int R, C, bx, by;
    if (bid < 2048 + 3072) {
        int g = bid - 2048;
        in = wqkv; out = wqkvT; R = 1024; C = 3072;
        bx = g % 96; by = g / 96;
    } else {
        int g = bid - 5120;
        in = wproj; out = wprojT; R = 1024; C = 1024;
        bx = g & 31; by = g >> 5;
    }
    const int c0 = bx * 32, r0 = by * 32;
    const int xx = threadIdx.x & 31, yy0 = threadIdx.x >> 5;
    #pragma unroll
    for (int yy = yy0; yy < 32; yy += 8)
        t[yy][xx] = in[(size_t)(r0 + yy) * C + (c0 + xx)];
    __syncthreads();
    #pragma unroll
    for (int yy = yy0; yy < 32; yy += 8)
        out[(size_t)(c0 + yy) * R + (r0 + xx)] = f2bf(t[xx][yy]);
}

// ---------------- QKV GEMM: C[4096x3072] = A * Bt^T (R7 form, T1 mapping) -------------
// col 0..7 = Q (swapped MFMA, scaled), 8..15 = K (swapped), 16..23 = V (unswapped,
// direct b64 stores to vT [bh][d][s]).
__global__ __launch_bounds__(256) void gemm_qkv_kernel(const unsigned short* __restrict__ A,
                                                       const unsigned short* __restrict__ Bt,
                                                       const float* __restrict__ bias,
                                                       unsigned short* __restrict__ q,
                                                       unsigned short* __restrict__ k,
                                                       unsigned short* __restrict__ vT) {
    __shared__ unsigned short As[128 * 64];
    __shared__ unsigned short Bs[128 * 64];
    const int tid = threadIdx.x;
    const int lane = tid & 63, wave = tid >> 6;
    const int l15 = lane & 15, quad = lane >> 4;
    const int wm = wave >> 1, wn = wave & 1;
    // T1 mapping: xcd = bid&7 (round-robin dispatch) owns cols {3*xcd..3*xcd+2};
    // within XCD, col varies fastest so co-resident blocks share the A-panel.
    const int bid = blockIdx.x;
    const int xcd = bid & 7, j = bid >> 3;   // j 0..95
    const int col = xcd * 3 + j % 3;         // 0..23
    const int row0 = (j / 3) * 128, col0 = col * 128;
    const int K = 1024;
    const bool isV = (col >= 16);

    int srow[4], scol[4], sdst[4];
    #pragma unroll
    for (int h = 0; h < 4; ++h) {
        int D = h * 256 + wave * 64 + lane;
        srow[h] = D >> 3;
        scol[h] = ((D & 7) ^ (srow[h] & 7)) * 8;
        sdst[h] = (h * 256 + wave * 64) * 8;
    }

    f32x4 acc[4][4] = {};

    for (int kt = 0; kt < K; kt += 64) {
        #pragma unroll
        for (int h = 0; h < 4; ++h) {
            gl_lds16(&A[(size_t)(row0 + srow[h]) * K + kt + scol[h]], &As[sdst[h]]);
            gl_lds16(&Bt[(size_t)(col0 + srow[h]) * K + kt + scol[h]], &Bs[sdst[h]]);
        }
        __syncthreads();
        #pragma unroll
        for (int kk = 0; kk < 2; ++kk) {
            short8 af[4], bf[4];
            #pragma unroll
            for (int i = 0; i < 4; ++i) {
                int r = wm * 64 + i * 16 + l15;
                af[i] = *(const short8*)&As[r * 64 + (((kk * 4 + quad) ^ (r & 7)) * 8)];
            }
            #pragma unroll
            for (int j2 = 0; j2 < 4; ++j2) {
                int r = wn * 64 + j2 * 16 + l15;
                bf[j2] = *(const short8*)&Bs[r * 64 + (((kk * 4 + quad) ^ (r & 7)) * 8)];
            }
            if (isV) {
                #pragma unroll
                for (int i = 0; i < 4; ++i)
                    #pragma unroll
                    for (int j2 = 0; j2 < 4; ++j2)
                        acc[i][j2] = MFMA_B16(af[i], bf[j2], acc[i][j2]);  // C
            } else {
                #pragma unroll
                for (int i = 0; i < 4; ++i)
                    #pragma unroll
                    for (int j2 = 0; j2 < 4; ++j2)
                        acc[i][j2] = MFMA_B16(bf[j2], af[i], acc[i][j2]);  // C^T
            }
        }
        __syncthreads();
    }

    const int b = row0 >> 11;
    const int s0 = row0 & 2047;
    const float* bb = bias + col0 + wn * 64;

    if (!isV) {
        // C^T: lane holds d = j*16 + quad*4 + {0..3} for s = wm*64 + i*16 + l15
        const int which = col >> 3;  // 0=Q, 1=K
        unsigned short* dst = which ? k : q;
        const float scale = which ? 1.0f : 0.1803368867f;  // 1/8 * log2(e) for Q
        const int hh = ((col & 7) << 1) + wn;
        #pragma unroll
        for (int i = 0; i < 4; ++i) {
            const int s = s0 + wm * 64 + i * 16 + l15;
            unsigned short* drow = dst + ((size_t)((b * 16 + hh) * 2048 + s)) * 64;
            #pragma unroll
            for (int j2 = 0; j2 < 4; ++j2) {
                float4 b4 = ((const float4*)bb)[j2 * 4 + quad];
                uint2 pv;
                pv.x = pk_bf16((acc[i][j2][0] + b4.x) * scale, (acc[i][j2][1] + b4.y) * scale);
                pv.y = pk_bf16((acc[i][j2][2] + b4.z) * scale, (acc[i][j2][3] + b4.w) * scale);
                *(uint2*)&drow[j2 * 16 + quad * 4] = pv;
            }
        }
    } else {
        // C: lane holds s = wm*64 + i*16 + quad*4 + {0..3} for d = j*16 + l15
        const int hh = ((col - 16) << 1) + wn;
        #pragma unroll
        for (int j2 = 0; j2 < 4; ++j2) {
            const int d = j2 * 16 + l15;
            const float bv = bb[d];
            unsigned short* drow = vT + ((size_t)((b * 16 + hh) * 64 + d)) * 2048 + s0;
            #pragma unroll
            for (int i = 0; i < 4; ++i) {
                uint2 pv;
                pv.x = pk_bf16(acc[i][j2][0] + bv, acc[i][j2][1] + bv);
                pv.y = pk_bf16(acc[i][j2][2] + bv, acc[i][j2][3] + bv);
                *(uint2*)&drow[wm * 64 + i * 16 + quad * 4] = pv;
            }
        }
    }
}

// ---------------- proj GEMM: out[4096x1024] fp32 = A * Bt^T + bias (R7 form) -------
__global__ __launch_bounds__(256) void gemm_proj_kernel(const unsigned short* __restrict__ A,
                                                        const unsigned short* __restrict__ Bt,
                                                        const float* __restrict__ bias,
                                                        float* __restrict__ out) {
    __shared__ unsigned short As[128 * 64];
    __shared__ unsigned short Bs[64 * 64];
    const int tid = threadIdx.x;
    const int lane = tid & 63, wave = tid >> 6;
    const int l15 = lane & 15, quad = lane >> 4;
    const int wm = wave >> 1, wn = wave & 1;
    const int row0 = blockIdx.y * 128, col0 = blockIdx.x * 64;
    const int K = 1024;

    int srow[4], scol[4], sdst[4];
    #pragma unroll
    for (int h = 0; h < 4; ++h) {
        int D = h * 256 + wave * 64 + lane;
        srow[h] = D >> 3;
        scol[h] = ((D & 7) ^ (srow[h] & 7)) * 8;
        sdst[h] = (h * 256 + wave * 64) * 8;
    }

    f32x4 acc[4][2] = {};

    for (int kt = 0; kt < K; kt += 64) {
        #pragma unroll
        for (int h = 0; h < 4; ++h)
            gl_lds16(&A[(size_t)(row0 + srow[h]) * K + kt + scol[h]], &As[sdst[h]]);
        #pragma unroll
        for (int h = 0; h < 2; ++h)
            gl_lds16(&Bt[(size_t)(col0 + srow[h]) * K + kt + scol[h]], &Bs[sdst[h]]);
        __syncthreads();
        #pragma unroll
        for (int kk = 0; kk < 2; ++kk) {
            short8 af[4], bf[2];
            #pragma unroll
            for (int i = 0; i < 4; ++i) {
                int r = wm * 64 + i * 16 + l15;
                af[i] = *(const short8*)&As[r * 64 + (((kk * 4 + quad) ^ (r & 7)) * 8)];
            }
            #pragma unroll
            for (int j = 0; j < 2; ++j) {
                int r = wn * 32 + j * 16 + l15;
                bf[j] = *(const short8*)&Bs[r * 64 + (((kk * 4 + quad) ^ (r & 7)) * 8)];
            }
            #pragma unroll
            for (int i = 0; i < 4; ++i)
                #pragma unroll
                for (int j = 0; j < 2; ++j)
                    acc[i][j] = MFMA_B16(bf[j], af[i], acc[i][j]);  // C^T
        }
        __syncthreads();
    }

    const float* bb = bias + col0 + wn * 32;
    #pragma unroll
    for (int i = 0; i < 4; ++i) {
        const int row = row0 + wm * 64 + i * 16 + l15;
        #pragma unroll
        for (int j = 0; j < 2; ++j) {
            float4 b4 = ((const float4*)bb)[j * 4 + quad];
            float4 ov;
            ov.x = acc[i][j][0] + b4.x;
            ov.y = acc[i][j][1] + b4.y;
            ov.z = acc[i][j][2] + b4.z;
            ov.w = acc[i][j][3] + b4.w;
            *(float4*)&out[(size_t)row * 1024 + col0 + wn * 32 + j * 16 + quad * 4] = ov;
        }
    }
}

// ---------------- flash attention (byte-exact R13) -------------
// smem (shorts): [0..16383] Ks[2][2 halves][64x64] | [16384..32767] Vs[2][2][64x64]
//                | [32768..40959] Pw[8][1024].  Total 80KB -> 2 blocks/CU.
__global__ __launch_bounds__(512) void attn_kernel(const unsigned short* __restrict__ Q,
                                                   const unsigned short* __restrict__ Kg,
                                                   const unsigned short* __restrict__ Vt,
                                                   const int* __restrict__ idx,
                                                   const float* __restrict__ weight,
                                                   const int* __restrict__ forcing,
                                                   unsigned short* __restrict__ O) {
    __shared__ unsigned short smem[40960];

    const int tid = threadIdx.x;
    const int lane = tid & 63, wave = tid >> 6;
    const int l15 = lane & 15, quad = lane >> 4;
    const int bid = blockIdx.x;
    const int qh = bid >> 8;
    const int rem = bid & 255;
    const int xcd = rem & 7;
    const int head = (rem >> 3) & 3;
    const int g2 = rem >> 5;          // 0..7
    const int p = qh ? (7 - g2) : (8 + g2);
    const int bh = xcd * 4 + head;
    const int b = bh >> 4, hh = bh & 15;
    const unsigned short* Qb = Q + (size_t)bh * 2048 * 64;
    const unsigned short* Kh = Kg + (size_t)bh * 2048 * 64;
    const unsigned short* Vh = Vt + (size_t)bh * 2048 * 64;

    const int idxb = idx[b];
    const float lw = (forcing[0] != 0) ? __log2f(weight[0]) : 0.0f;

    const int wq = 2 * p + ((wave < 4) ? 1 : 0);
    const int wg = wave & 3;
    const int q0 = wq * 64 + wg * 16;
    const int qrow = q0 + l15;
    const int nkb = p + 1;            // 128-wide k-tiles

    const int rS = tid >> 3;
    const int cS8 = ((tid & 7) ^ (rS & 7)) * 8;

    short8 aq0 = *(const short8*)&Qb[(q0 + l15) * 64 + quad * 8];
    short8 aq1 = *(const short8*)&Qb[(q0 + l15) * 64 + 32 + quad * 8];

    const short8 ones8 = {0x3F80, 0x3F80, 0x3F80, 0x3F80, 0x3F80, 0x3F80, 0x3F80, 0x3F80};

    f32x4 o[4] = {};
    f32x4 lsum = {};

    gl_lds16(Kh + (size_t)rS * 64 + cS8,             &smem[tid * 8]);
    gl_lds16(Kh + (size_t)(64 + rS) * 64 + cS8,      &smem[4096 + tid * 8]);
    gl_lds16(Vh + (size_t)rS * 2048 + cS8,           &smem[16384 + tid * 8]);
    gl_lds16(Vh + (size_t)rS * 2048 + 64 + cS8,      &smem[16384 + 4096 + tid * 8]);
    __syncthreads();

    unsigned short* const pwb = &smem[32768 + wave * 1024];
    const int pwr = l15 * 64;
    const int pa7 = l15 & 7;

    for (int kb = 0; kb < nkb; ++kb) {
        const int cur = kb & 1;
        const int kbase = kb * 128;
        if (kb + 1 < nkb) {
            const int nb = kbase + 128;
            gl_lds16(Kh + (size_t)(nb + rS) * 64 + cS8,      &smem[(cur ^ 1) * 8192 + tid * 8]);
            gl_lds16(Kh + (size_t)(nb + 64 + rS) * 64 + cS8, &smem[(cur ^ 1) * 8192 + 4096 + tid * 8]);
            gl_lds16(Vh + (size_t)rS * 2048 + nb + cS8,      &smem[16384 + (cur ^ 1) * 8192 + tid * 8]);
            gl_lds16(Vh + (size_t)rS * 2048 + nb + 64 + cS8, &smem[16384 + (cur ^ 1) * 8192 + 4096 + tid * 8]);
        }

        const unsigned short* KsP = &smem[cur * 8192];
        const unsigned short* VsP = &smem[16384 + cur * 8192];

        const bool fullF = (kbase >= idxb);
        const bool bndF = (!fullF) && (kbase + 127 >= idxb);
        const float zu = fullF ? lw : 0.0f;

        f32x4 sT[8];
        #pragma unroll
        for (int kt = 0; kt < 8; ++kt) {
            const int lr = (kt & 3) * 16 + l15;
            const unsigned short* Kp = KsP + (kt >> 2) * 4096;
            short8 k0 = *(const short8*)&Kp[lr * 64 + ((quad ^ (lr & 7)) * 8)];
            short8 k1 = *(const short8*)&Kp[lr * 64 + (((4 + quad) ^ (lr & 7)) * 8)];
            f32x4 z;
            if (!bndF) {
                z[0] = zu; z[1] = zu; z[2] = zu; z[3] = zu;
            } else {
                #pragma unroll
                for (int r = 0; r < 4; ++r)
                    z[r] = (kbase + kt * 16 + quad * 4 + r >= idxb) ? lw : 0.0f;
            }
            z = MFMA_B16(k0, aq0, z);
            z = MFMA_B16(k1, aq1, z);
            sT[kt] = z;
        }

        if (kb == nkb - 1) {
            #pragma unroll
            for (int kt = 0; kt < 8; ++kt)
                #pragma unroll
                for (int r = 0; r < 4; ++r)
                    if (kbase + kt * 16 + quad * 4 + r > qrow) sT[kt][r] = -3.0e38f;
        }

        #pragma unroll
        for (int kt = 0; kt < 8; ++kt)
            #pragma unroll
            for (int r = 0; r < 4; ++r)
                sT[kt][r] = EXP2(sT[kt][r]);

        #pragma unroll
        for (int h = 0; h < 2; ++h) {
            #pragma unroll
            for (int kt = 0; kt < 4; ++kt) {
                f32x4 s = sT[h * 4 + kt];
                unsigned int* pw = (unsigned int*)&pwb[pwr +
                    (((kt * 2 + (quad >> 1)) ^ pa7) * 8) + (quad & 1) * 4];
                pw[0] = pk_bf16(s[0], s[1]);
                pw[1] = pk_bf16(s[2], s[3]);
            }

            short8 bp0 = *(const short8*)&pwb[pwr + ((quad ^ pa7) * 8)];
            short8 bp1 = *(const short8*)&pwb[pwr + (((4 + quad) ^ pa7) * 8)];

            lsum = MFMA_B16(ones8, bp0, lsum);
            lsum = MFMA_B16(ones8, bp1, lsum);

            const unsigned short* Vp = VsP + h * 4096;
            #pragma unroll
            for (int dt = 0; dt < 4; ++dt) {
                const int row = dt * 16 + l15;
                short8 vf0 = *(const short8*)&Vp[row * 64 + ((quad ^ (row & 7)) * 8)];
                short8 vf1 = *(const short8*)&Vp[row * 64 + (((4 + quad) ^ (row & 7)) * 8)];
                f32x4 oo = o[dt];
                oo = MFMA_B16(vf0, bp0, oo);
                oo = MFMA_B16(vf1, bp1, oo);
                o[dt] = oo;
            }
        }

        __syncthreads();
    }

    const float inv = 1.0f / lsum[0];
    unsigned short* sc = &smem[wave * 1152];
    #pragma unroll
    for (int dt = 0; dt < 4; ++dt)
        #pragma unroll
        for (int r = 0; r < 4; ++r)
            sc[l15 * 72 + dt * 16 + quad * 4 + r] = f2bf(o[dt][r] * inv);
    const size_t rowoff = ((size_t)(b * 2048 + q0 + l15)) * 1024 + hh * 64;
    #pragma unroll
    for (int h = 0; h < 2; ++h) {
        short8 v8 = *(const short8*)&sc[l15 * 72 + quad * 16 + h * 8];
        *(short8*)&O[rowoff + quad * 16 + h * 8] = v8;
    }
}

extern "C" void kernel_launch(void* const* d_in, const int* in_sizes, int n_in,
                              void* d_out, int out_size, void* d_ws, size_t ws_size,
                              hipStream_t stream) {
    const float* x        = (const float*)d_in[0];
    const int*   idx      = (const int*)d_in[1];
    const float* weight   = (const float*)d_in[2];
    const int*   forcing  = (const int*)d_in[3];
    const float* w_qkv    = (const float*)d_in[4];
    const float* b_qkv    = (const float*)d_in[5];
    const float* w_proj   = (const float*)d_in[6];
    const float* b_proj   = (const float*)d_in[7];
    float* out = (float*)d_out;

    char* ws = (char*)d_ws;
    unsigned short* xb      = (unsigned short*)(ws);              // 8 MB (reused: attn_out)
    unsigned short* wqkvT   = (unsigned short*)(ws + 8388608);    // 6 MB
    unsigned short* wprojT  = (unsigned short*)(ws + 14680064);   // 2 MB
    unsigned short* qbuf    = (unsigned short*)(ws + 16777216);   // 8 MB
    unsigned short* kbuf    = (unsigned short*)(ws + 25165824);   // 8 MB
    unsigned short* vTbuf   = (unsigned short*)(ws + 33554432);   // 8 MB
    unsigned short* attn_out = xb;  // xb dead after gemm_qkv

    prep_kernel<<<6144, 256, 0, stream>>>((const float4*)x, (uint4*)xb,
                                          w_qkv, wqkvT, w_proj, wprojT);
    gemm_qkv_kernel<<<768, 256, 0, stream>>>(xb, wqkvT, b_qkv, qbuf, kbuf, vTbuf);
    attn_kernel<<<512, 512, 0, stream>>>(qbuf, kbuf, vTbuf, idx, weight, forcing, attn_out);
    gemm_proj_kernel<<<dim3(16, 32), 256, 0, stream>>>(attn_out, wprojT, b_proj, out);
}